// Round 6
// baseline (162290.930 us; speedup 1.0000x reference)
//
#include <hip/hip_runtime.h>
#include <stdint.h>

// ---------------------------------------------------------------------------
// BioDecoder: 64-step LSTM decoder w/ attention, rep-penalty, temperature=0.4,
// top-p=0.7, jax.random.categorical (Threefry partitionable). All fp32.
// Association discipline: every dot = strict sequential-k single-acc fma chain.
// R8: persistent kernel, barrier overhaul. R7 counters: VALUBusy 6.3% -> the
// 70ms was gsync spin (one hot cache line + 128-cyc poll + 15 barriers/step).
// Fixes: (1) cnt/gen on separate 256B lines + s_sleep(32) poll; (2) 15->7
// barriers/step: sampler = 1 block/batch (internal gsyncs -> __syncthreads,
// 1024-thr reduction trees emulated bit-exactly via 4 partials + exact
// pairing); gate GEMM fused into attn block via once-transposed Wg1.
// All arithmetic associations identical to R7 (passed, absmax 0).
// ---------------------------------------------------------------------------

#define B_   64
#define H_   1024
#define E_   512
#define DV_  512
#define KV_  49
#define V_   32000
#define T_   64
#define NBLK 256

// ------------------------- Threefry-2x32-20 (JAX) --------------------------
__device__ __forceinline__ uint32_t rotl32(uint32_t x, int r) {
  return (x << r) | (x >> (32 - r));
}
__device__ __forceinline__ void tf2x32(uint32_t k0, uint32_t k1,
                                       uint32_t x0, uint32_t x1,
                                       uint32_t& o0, uint32_t& o1) {
  uint32_t ks0 = k0, ks1 = k1, ks2 = k0 ^ k1 ^ 0x1BD11BDAu;
  x0 += ks0; x1 += ks1;
#define RND_(r) { x0 += x1; x1 = rotl32(x1, r) ^ x0; }
  RND_(13) RND_(15) RND_(26) RND_(6)  x0 += ks1; x1 += ks2 + 1u;
  RND_(17) RND_(29) RND_(16) RND_(24) x0 += ks2; x1 += ks0 + 2u;
  RND_(13) RND_(15) RND_(26) RND_(6)  x0 += ks0; x1 += ks1 + 3u;
  RND_(17) RND_(29) RND_(16) RND_(24) x0 += ks1; x1 += ks2 + 4u;
  RND_(13) RND_(15) RND_(26) RND_(6)  x0 += ks2; x1 += ks0 + 5u;
#undef RND_
  o0 = x0; o1 = x1;
}

__device__ __forceinline__ unsigned key_of(float f) {
  unsigned u = __float_as_uint(f);
  return (u & 0x80000000u) ? ~u : (u | 0x80000000u);
}
__device__ __forceinline__ float sigf(float x) { return 1.0f / (1.0f + expf(-x)); }

// ------------------------- software grid barrier ---------------------------
// bar[0] = arrival count (line 0), bar[64] = generation (line +256B).
// Separate lines: arriving RMWs don't ping-pong against spin loads.
// s_sleep(32) ~ 2048 cyc poll interval: ~16x less coherence traffic than R7.
__device__ __forceinline__ void gsync(unsigned* bar) {
  __syncthreads();
  if (threadIdx.x == 0) {
    __threadfence();
    unsigned g = __hip_atomic_load(bar + 64, __ATOMIC_RELAXED, __HIP_MEMORY_SCOPE_AGENT);
    unsigned a = __hip_atomic_fetch_add(bar, 1u, __ATOMIC_ACQ_REL, __HIP_MEMORY_SCOPE_AGENT);
    if (a + 1u == (unsigned)NBLK) {
      __hip_atomic_store(bar, 0u, __ATOMIC_RELAXED, __HIP_MEMORY_SCOPE_AGENT);
      __hip_atomic_store(bar + 64, g + 1u, __ATOMIC_RELEASE, __HIP_MEMORY_SCOPE_AGENT);
    } else {
      while (__hip_atomic_load(bar + 64, __ATOMIC_ACQUIRE, __HIP_MEMORY_SCOPE_AGENT) == g)
        __builtin_amdgcn_s_sleep(32);
    }
  }
  __syncthreads();
}

__global__ void bar_init(unsigned* bar) {
  if (threadIdx.x < 128) bar[threadIdx.x] = 0u;
}

// ------------------------- device GEMM tile (verbatim R7) ------------------
template <int BN, int TM, int TN, int NTHR>
__device__ void gemm_tile(int tid, float* Sb0, int n0, int m0,
                          const float* __restrict__ A, int lda,
                          const float* __restrict__ W, int ldw, int K,
                          float* __restrict__ out, int ldo) {
  constexpr int LD = 36;
  constexpr int ROWS = 64 + BN;
  constexpr int NF4 = ROWS * 8 / NTHR;
  constexpr int BUFST = ROWS * LD;
  constexpr int CG = BN / TN;
  static_assert(ROWS * 8 % NTHR == 0, "staging divisibility");
  static_assert((64 / TM) * CG == NTHR, "thread grid");
  static_assert(TN == 4, "float4 epilogue");
  const bool act = tid < NTHR;
  const int tc = tid % CG, tr = tid / CG;
  const float* gp[NF4];
  float* lp[NF4];
  float4 pre[NF4];
  if (act) {
#pragma unroll
    for (int q = 0; q < NF4; ++q) {
      int l = tid + q * NTHR;
      int r = l >> 3, c4 = l & 7;
      gp[q] = (l < 512) ? (A + (m0 + r) * lda + c4 * 4)
                        : (W + (n0 + (r - 64)) * ldw + c4 * 4);
      lp[q] = Sb0 + r * LD + ((c4 ^ ((r >> 2) & 7)) << 2);
    }
#pragma unroll
    for (int q = 0; q < NF4; ++q) pre[q] = *(const float4*)gp[q];
#pragma unroll
    for (int q = 0; q < NF4; ++q) *(float4*)lp[q] = pre[q];
  }
  __syncthreads();
  float acc[TM][TN] = {};
  const int nch = K >> 5;
  for (int c = 0; c < nch; ++c) {
    const bool more = (c + 1 < nch);
    if (act && more) {
      const int kc = (c + 1) << 5;
#pragma unroll
      for (int q = 0; q < NF4; ++q) pre[q] = *(const float4*)(gp[q] + kc);
    }
    if (act) {
      const float* Sb = Sb0 + (c & 1) * BUFST;
#pragma unroll
      for (int kk = 0; kk < 8; ++kk) {
        float4 a4[TM], w4[TN];
#pragma unroll
        for (int i = 0; i < TM; ++i) {
          int m = tr * TM + i;
          a4[i] = *(const float4*)(Sb + m * LD + ((kk ^ ((m >> 2) & 7)) << 2));
        }
#pragma unroll
        for (int j = 0; j < TN; ++j) {
          int rw = 64 + tc * TN + j;
          w4[j] = *(const float4*)(Sb + rw * LD + ((kk ^ ((rw >> 2) & 7)) << 2));
        }
#pragma unroll
        for (int i = 0; i < TM; ++i)
#pragma unroll
          for (int j = 0; j < TN; ++j) {
            acc[i][j] = fmaf(a4[i].x, w4[j].x, acc[i][j]);
            acc[i][j] = fmaf(a4[i].y, w4[j].y, acc[i][j]);
            acc[i][j] = fmaf(a4[i].z, w4[j].z, acc[i][j]);
            acc[i][j] = fmaf(a4[i].w, w4[j].w, acc[i][j]);
          }
      }
    }
    if (act && more) {
      const int bo2 = ((c + 1) & 1) * BUFST;
#pragma unroll
      for (int q = 0; q < NF4; ++q) *(float4*)(lp[q] + bo2) = pre[q];
    }
    __syncthreads();
  }
  if (act) {
#pragma unroll
    for (int i = 0; i < TM; ++i) {
      float4 o;
      o.x = acc[i][0]; o.y = acc[i][1]; o.z = acc[i][2]; o.w = acc[i][3];
      *(float4*)&out[(m0 + tr * TM + i) * ldo + n0 + tc * TN] = o;
    }
  }
}

// ------------------------- LDS overlays ------------------------------------
struct LnLds   { float buf[H_]; float red[256]; };
struct AttnLds { float t1[H_]; float outv[H_]; float attn[64]; float gate; };
struct SamLds  {
  float redf[256]; int redi[256];
  unsigned long long whist[4][257];
  unsigned long long suf[256];
  unsigned long long wq[4];
  unsigned long long carry;
  unsigned prefix;
  int jstar;
};

// ------------------------- param pack --------------------------------------
struct MegaP {
  const float *thought, *visf, *embedding;
  const float *Wih1, *Whh1, *bih1, *bhh1;
  const float *Wih2, *Whh2, *bih2, *bhh2;
  const float *Wg1, *bg1, *Wg2, *bg2;
  const float *Wo, *bo, *Wv, *bv, *ln_g, *ln_b;
  float *vp, *xcat1, *xcat2, *c1, *c2, *h2buf, *ctx, *dx, *dh, *dlog, *Lb, *Eb;
  float *WgT;
  int *hist, *histv, *outTok;
  unsigned *bar;
};

// ------------------------- the persistent kernel ---------------------------
__global__ __launch_bounds__(256, 1)
void mega(MegaP p) {
  __shared__ __align__(16) unsigned char LDSU_[55296];  // 2*(64+128)*36*4
  float* GS = (float*)LDSU_;
  const int bx = blockIdx.x;
  const int tid = threadIdx.x;

  // ---- P0: init_state + Wg1 transpose + visual_proj GEMM ----
  {
    int i = bx * 256 + tid;
    if (i < B_ * H_) {
      int b = i >> 10, h = i & 1023;
      p.c1[i] = 0.f; p.c2[i] = 0.f;
      float th = p.thought[i];
      p.xcat1[b * (E_ + H_) + E_ + h] = th;
      p.xcat2[b * (2 * H_) + H_ + h] = th;
      if (h < E_) p.xcat1[b * (E_ + H_) + h] = p.embedding[E_ + h];
    }
    if (i < B_ * 3) { p.hist[i] = 0; p.histv[i] = 0; }
  }
  for (int i = bx * 256 + tid; i < H_ * H_; i += NBLK * 256) {
    int j = i >> 10, k = i & 1023;
    p.WgT[k * H_ + j] = p.Wg1[i];     // WgT[k][j] = Wg1[j][k]
  }
  for (int s = bx; s < 8 * KV_; s += NBLK)
    gemm_tile<128, 8, 4, 256>(tid, GS, (s & 7) * 128, (s >> 3) * 64,
                              p.visf, DV_, p.Wv, DV_, DV_, p.vp, H_);
  gsync(p.bar);

  // ---- P1: LayerNorm over 3136 rows (verbatim) ----
  for (int row = bx; row < B_ * KV_; row += NBLK) {
    LnLds& LL = *(LnLds*)LDSU_;
    float* pp = p.vp + (long long)row * H_;
    for (int h = tid; h < H_; h += 256) LL.buf[h] = __fadd_rn(pp[h], p.bv[h]);
    __syncthreads();
    float s = 0;
    for (int h = tid; h < H_; h += 256) s += LL.buf[h];
    LL.red[tid] = s; __syncthreads();
    for (int off = 128; off > 0; off >>= 1) { if (tid < off) LL.red[tid] += LL.red[tid + off]; __syncthreads(); }
    float mu = LL.red[0] / (float)H_;
    __syncthreads();
    float vs = 0;
    for (int h = tid; h < H_; h += 256) { float d = LL.buf[h] - mu; vs += d * d; }
    LL.red[tid] = vs; __syncthreads();
    for (int off = 128; off > 0; off >>= 1) { if (tid < off) LL.red[tid] += LL.red[tid + off]; __syncthreads(); }
    float var = LL.red[0] / (float)H_;
    float sq = sqrtf(var + 1e-5f);
    for (int h = tid; h < H_; h += 256) {
      float nrm = __fdiv_rn(__fsub_rn(LL.buf[h], mu), sq);
      pp[h] = __fadd_rn(__fmul_rn(nrm, p.ln_g[h]), p.ln_b[h]);
    }
    __syncthreads();
  }
  gsync(p.bar);

  // ---- decode loop: 7 gsyncs/step ----
  for (int t = 0; t < T_; ++t) {
    // [1] L1 GEMM: dx = emb @ Wih1^T (K=512) | dh = h1 @ Whh1^T (K=1024)
    if (bx < 128)
      gemm_tile<32, 4, 4, 128>(tid, GS, bx * 32, 0,
                               p.xcat1, E_ + H_, p.Wih1, E_, E_, p.dx, 4096);
    else
      gemm_tile<32, 4, 4, 128>(tid, GS, (bx - 128) * 32, 0,
                               p.xcat1 + E_, E_ + H_, p.Whh1, H_, H_, p.dh, 4096);
    gsync(p.bar);
    // [2] lstm1 (verbatim)
    {
      int idx = bx * 256 + tid;
      int b = idx >> 10, h = idx & 1023;
      float z[4];
#pragma unroll
      for (int g = 0; g < 4; g++) {
        int j = g * 1024 + h;
        float s = __fadd_rn(p.dx[b * 4096 + j], p.dh[b * 4096 + j]);
        s = __fadd_rn(s, p.bih1[j]);
        s = __fadd_rn(s, p.bhh1[j]);
        z[g] = s;
      }
      float fc = __fmul_rn(sigf(z[1]), p.c1[idx]);
      float ig = __fmul_rn(sigf(z[0]), tanhf(z[2]));
      float cn = __fadd_rn(fc, ig);
      float hn = __fmul_rn(sigf(z[3]), tanhf(cn));
      p.c1[idx] = cn;
      p.xcat1[(long long)b * (E_ + H_) + E_ + h] = hn;
      p.xcat2[(long long)b * (2 * H_) + h] = hn;
    }
    gsync(p.bar);
    // [3] L2 GEMM
    if (bx < 128)
      gemm_tile<32, 4, 4, 128>(tid, GS, bx * 32, 0,
                               p.xcat2, 2 * H_, p.Wih2, H_, H_, p.dx, 4096);
    else
      gemm_tile<32, 4, 4, 128>(tid, GS, (bx - 128) * 32, 0,
                               p.xcat2 + H_, 2 * H_, p.Whh2, H_, H_, p.dh, 4096);
    gsync(p.bar);
    // [4] lstm2 (verbatim)
    {
      int idx = bx * 256 + tid;
      int b = idx >> 10, h = idx & 1023;
      float z[4];
#pragma unroll
      for (int g = 0; g < 4; g++) {
        int j = g * 1024 + h;
        float s = __fadd_rn(p.dx[b * 4096 + j], p.dh[b * 4096 + j]);
        s = __fadd_rn(s, p.bih2[j]);
        s = __fadd_rn(s, p.bhh2[j]);
        z[g] = s;
      }
      float fc = __fmul_rn(sigf(z[1]), p.c2[idx]);
      float ig = __fmul_rn(sigf(z[0]), tanhf(z[2]));
      float cn = __fadd_rn(fc, ig);
      float hn = __fmul_rn(sigf(z[3]), tanhf(cn));
      p.c2[idx] = cn;
      p.h2buf[(long long)b * H_ + h] = hn;
      p.xcat2[(long long)b * (2 * H_) + H_ + h] = hn;
    }
    gsync(p.bar);
    // [5] fused gate-GEMM + gate + attention (64 blocks, one per batch)
    if (bx < B_) {
      AttnLds& AL = *(AttnLds*)LDSU_;
      const int b = bx;
      // dg[h] for h in {tid,+256,+512,+768}: sequential k-chain (same
      // association as the old gate GEMM: k ascending, single acc each).
      float s0 = 0, s1 = 0, s2 = 0, s3 = 0;
      for (int k = 0; k < H_; ++k) {
        float hk = p.h2buf[b * H_ + k];          // uniform -> scalar load
        const float* wr = p.WgT + k * H_;
        s0 = fmaf(hk, wr[tid], s0);
        s1 = fmaf(hk, wr[tid + 256], s1);
        s2 = fmaf(hk, wr[tid + 512], s2);
        s3 = fmaf(hk, wr[tid + 768], s3);
      }
      AL.t1[tid]       = tanhf(__fadd_rn(s0, p.bg1[tid]));
      AL.t1[tid + 256] = tanhf(__fadd_rn(s1, p.bg1[tid + 256]));
      AL.t1[tid + 512] = tanhf(__fadd_rn(s2, p.bg1[tid + 512]));
      AL.t1[tid + 768] = tanhf(__fadd_rn(s3, p.bg1[tid + 768]));
      __syncthreads();
      if (tid == 0) {
        float s = 0;
        for (int h = 0; h < H_; h++) s = fmaf(AL.t1[h], p.Wg2[h], s);
        AL.gate = sigf(__fadd_rn(s, p.bg2[0]));
      }
      __syncthreads();
      float gate = AL.gate;
      for (int h = tid; h < H_; h += 256) AL.outv[h] = __fmul_rn(p.h2buf[b * H_ + h], gate);
      __syncthreads();
      if (tid < KV_) {
        const float* vrow = p.vp + ((long long)b * KV_ + tid) * H_;
        float a = 0;
        for (int h = 0; h < H_; h++) a = fmaf(AL.outv[h], vrow[h], a);
        AL.attn[tid] = __fmul_rn(a, 0.03125f);
      }
      __syncthreads();
      if (tid == 0) {
        float m = -INFINITY;
        for (int k = 0; k < KV_; k++) m = fmaxf(m, AL.attn[k]);
        float ss = 0;
        for (int k = 0; k < KV_; k++) { AL.attn[k] = expf(AL.attn[k] - m); ss += AL.attn[k]; }
        for (int k = 0; k < KV_; k++) AL.attn[k] = __fdiv_rn(AL.attn[k], ss);
      }
      __syncthreads();
      for (int h = tid; h < H_; h += 256) {
        float acc = 0;
        for (int k = 0; k < KV_; k++) acc = fmaf(AL.attn[k], p.vp[((long long)b * KV_ + k) * H_ + h], acc);
        p.ctx[b * H_ + h] = __fadd_rn(AL.outv[h], acc);
      }
    }
    gsync(p.bar);
    // [6] logits GEMM: dlog = ctx @ Wo^T (250 tiles of BN=128)
    if (bx < 250)
      gemm_tile<128, 8, 4, 256>(tid, GS, bx * 128, 0,
                                p.ctx, H_, p.Wo, H_, H_, p.dlog, V_);
    gsync(p.bar);
    // [7] sampler: ONE block per batch; 1024-thread trees emulated exactly.
    if (bx < B_) {
      const int b = bx;
      SamLds& SL = *(SamLds*)LDSU_;
      int hh0 = p.hist[b * 3 + 0], hh1 = p.hist[b * 3 + 1], hh2 = p.hist[b * 3 + 2];
      int q0 = p.histv[b * 3 + 0] ? hh0 : -1;
      int q1 = p.histv[b * 3 + 1] ? hh1 : -1;
      int q2 = p.histv[b * 3 + 2] ? hh2 : -1;
      const float* pa = p.dlog + (long long)b * V_;
      float* L = p.Lb + (long long)b * V_;
      float* E = p.Eb + (long long)b * V_;

      // pass 1: scaled logits + max (max is exact; tree pairing replicated)
      float lm0 = -INFINITY, lm1 = -INFINITY, lm2 = -INFINITY, lm3 = -INFINITY;
#define P1LOOP(LM, OFS)                                              \
      for (int v = tid + OFS; v < V_; v += 1024) {                   \
        float raw = __fadd_rn(pa[v], p.bo[v]);                       \
        if (v == q0 || v == q1 || v == q2) raw = __fsub_rn(raw, 2.0f);\
        float l = __fdiv_rn(raw, 0.4f);                              \
        L[v] = l;                                                    \
        LM = fmaxf(LM, l);                                           \
      }
      P1LOOP(lm0, 0) P1LOOP(lm1, 256) P1LOOP(lm2, 512) P1LOOP(lm3, 768)
#undef P1LOOP
      SL.redf[tid] = fmaxf(fmaxf(lm0, lm2), fmaxf(lm1, lm3));
      __syncthreads();
      for (int off = 128; off > 0; off >>= 1) { if (tid < off) SL.redf[tid] = fmaxf(SL.redf[tid], SL.redf[tid + off]); __syncthreads(); }
      float m = SL.redf[0];
      __syncthreads();

      // pass 2: exp + sum (exact old pairing: (s0+s2)+(s1+s3), then 256-tree)
      float s0 = 0, s1 = 0, s2 = 0, s3 = 0;
#define P2LOOP(SS, OFS)                                              \
      for (int v = tid + OFS; v < V_; v += 1024) {                   \
        float e = expf(L[v] - m); E[v] = e; SS += e;                 \
      }
      P2LOOP(s0, 0) P2LOOP(s1, 256) P2LOOP(s2, 512) P2LOOP(s3, 768)
#undef P2LOOP
      SL.redf[tid] = (s0 + s2) + (s1 + s3);
      __syncthreads();
      for (int off = 128; off > 0; off >>= 1) { if (tid < off) SL.redf[tid] += SL.redf[tid + off]; __syncthreads(); }
      float Z = SL.redf[0];
      __syncthreads();

      // radix select (integer, order-independent)
      const double SC = 17592186044416.0; // 2^44
      const unsigned long long B0 =
          (unsigned long long)(0.699999988079071044921875 * 17592186044416.0);
      if (tid == 0) { SL.carry = 0ull; SL.prefix = 0u; }
      __syncthreads();
      for (int pass = 0; pass < 4; pass++) {
        int shift = 24 - 8 * pass;
        unsigned maskk = (pass == 0) ? 0u : (0xFFFFFFFFu << (shift + 8));
        for (int i = tid; i < 4 * 257; i += 256) ((unsigned long long*)SL.whist)[i] = 0ull;
        __syncthreads();
        unsigned pref = SL.prefix;
        unsigned long long carry = SL.carry;
        for (int sub = 0; sub < 4; ++sub)
          for (int v = tid + (sub << 8); v < V_; v += 1024) {
            unsigned key = key_of(L[v]);
            if ((key & maskk) == pref) {
              unsigned bin = (key >> shift) & 255u;
              unsigned long long S = (unsigned long long)((double)(E[v] / Z) * SC);
              atomicAdd(&SL.whist[tid >> 6][bin], (S << 16) | 1ull);
            }
          }
        __syncthreads();
        unsigned long long bs =
            ((SL.whist[0][tid] + SL.whist[1][tid]) + SL.whist[2][tid]) + SL.whist[3][tid];
        if (tid == 0) SL.jstar = 256;
        __syncthreads();
        unsigned long long sown = bs >> 16;
        unsigned long long sincl = sown;
#pragma unroll
        for (int off = 1; off < 64; off <<= 1) {
          unsigned long long o = __shfl_down(sincl, off);
          if ((tid & 63) + off < 64) sincl += o;
        }
        if ((tid & 63) == 0) SL.wq[tid >> 6] = sincl;
        __syncthreads();
        {
          unsigned long long add = 0ull;
          for (int w2 = (tid >> 6) + 1; w2 < 4; ++w2) add += SL.wq[w2];
          SL.suf[tid] = sincl + add - sown;
        }
        __syncthreads();
        if ((unsigned)(bs & 0xFFFFull) > 0u) {
          unsigned long long A = carry + SL.suf[tid];
          if (A <= B0) atomicMin(&SL.jstar, tid);
        }
        __syncthreads();
        if (tid == 0) {
          int j = SL.jstar;
          SL.carry = carry + SL.suf[j];
          SL.prefix = pref | (((unsigned)j) << shift);
        }
        __syncthreads();
      }
      unsigned Kstar = SL.prefix;

      // step key
      unsigned kt0, kt1;
      tf2x32(0u, 42u, 0u, (unsigned)t, kt0, kt1);

      // gumbel argmax over kept set (old 1024-tree emulated exactly)
      float b0v = -INFINITY, b1v = -INFINITY, b2v = -INFINITY, b3v = -INFINITY;
      int b0i = 0x7fffffff, b1i = 0x7fffffff, b2i = 0x7fffffff, b3i = 0x7fffffff;
#define GLOOP(BV, BI, OFS)                                           \
      for (int v = tid + OFS; v < V_; v += 1024) {                   \
        float l = L[v];                                              \
        if (key_of(l) >= Kstar) {                                    \
          unsigned r0, r1;                                           \
          tf2x32(kt0, kt1, 0u, (unsigned)(b * V_ + v), r0, r1);      \
          unsigned bits = r0 ^ r1;                                   \
          float u = __uint_as_float((bits >> 9) | 0x3f800000u) - 1.0f;\
          u = fmaxf(u, 1.17549435e-38f);                             \
          float gum = -logf(-logf(u));                               \
          float val = __fadd_rn(l, gum);                             \
          if (val > BV) { BV = val; BI = v; }                        \
        }                                                            \
      }
      GLOOP(b0v, b0i, 0) GLOOP(b1v, b1i, 256) GLOOP(b2v, b2i, 512) GLOOP(b3v, b3i, 768)
#undef GLOOP
      // old off=512 pairing: (b0,b2) and (b1,b3); then off=256 combine
      float av = b0v; int ai = b0i;
      if (b2v > av || (b2v == av && b2i < ai)) { av = b2v; ai = b2i; }
      float bv = b1v; int bi2 = b1i;
      if (b3v > bv || (b3v == bv && b3i < bi2)) { bv = b3v; bi2 = b3i; }
      if (bv > av || (bv == av && bi2 < ai)) { av = bv; ai = bi2; }
      SL.redf[tid] = av; SL.redi[tid] = ai;
      __syncthreads();
      for (int off = 128; off > 0; off >>= 1) {
        if (tid < off) {
          float ov = SL.redf[tid + off]; int oi = SL.redi[tid + off];
          if (ov > SL.redf[tid] || (ov == SL.redf[tid] && oi < SL.redi[tid])) { SL.redf[tid] = ov; SL.redi[tid] = oi; }
        }
        __syncthreads();
      }
      int tok = SL.redi[0];
      if (tid == 0) {
        p.outTok[b * T_ + t] = tok;
        p.hist[b * 3 + 0] = hh1; p.hist[b * 3 + 1] = hh2; p.hist[b * 3 + 2] = tok;
        int v1h = p.histv[b * 3 + 1], v2h = p.histv[b * 3 + 2];
        p.histv[b * 3 + 0] = v1h; p.histv[b * 3 + 1] = v2h; p.histv[b * 3 + 2] = 1;
      }
      for (int k = tid; k < E_; k += 256)
        p.xcat1[b * (E_ + H_) + k] = p.embedding[(long long)tok * E_ + k];
    }
    gsync(p.bar);   // step end: xcat1/hist published for next step
  }
}

// ---------------------------------------------------------------------------
extern "C" void kernel_launch(void* const* d_in, const int* in_sizes, int n_in,
                              void* d_out, int out_size, void* d_ws, size_t ws_size,
                              hipStream_t stream) {
  MegaP p;
  p.thought   = (const float*)d_in[0];
  p.visf      = (const float*)d_in[1];
  p.embedding = (const float*)d_in[3];
  p.Wih1 = (const float*)d_in[4];
  p.Whh1 = (const float*)d_in[5];
  p.bih1 = (const float*)d_in[6];
  p.bhh1 = (const float*)d_in[7];
  p.Wih2 = (const float*)d_in[8];
  p.Whh2 = (const float*)d_in[9];
  p.bih2 = (const float*)d_in[10];
  p.bhh2 = (const float*)d_in[11];
  p.Wg1  = (const float*)d_in[12];
  p.bg1  = (const float*)d_in[13];
  p.Wg2  = (const float*)d_in[14];
  p.bg2  = (const float*)d_in[15];
  p.Wo   = (const float*)d_in[16];
  p.bo   = (const float*)d_in[17];
  p.Wv   = (const float*)d_in[18];
  p.bv   = (const float*)d_in[19];
  p.ln_g = (const float*)d_in[20];
  p.ln_b = (const float*)d_in[21];
  p.outTok = (int*)d_out;

  float* ws = (float*)d_ws;
  long long off = 0;
  p.vp    = ws + off; off += (long long)B_ * KV_ * H_;
  p.xcat1 = ws + off; off += B_ * (E_ + H_);
  p.xcat2 = ws + off; off += B_ * (2 * H_);
  p.c1    = ws + off; off += B_ * H_;
  p.c2    = ws + off; off += B_ * H_;
  p.h2buf = ws + off; off += B_ * H_;
  p.ctx   = ws + off; off += B_ * H_;
  p.dx    = ws + off; off += (long long)B_ * 4096;
  p.dh    = ws + off; off += (long long)B_ * 4096;
  p.dlog  = ws + off; off += (long long)B_ * V_;
  p.Lb    = ws + off; off += (long long)B_ * V_;
  p.Eb    = ws + off; off += (long long)B_ * V_;
  p.WgT   = ws + off; off += (long long)H_ * H_;
  p.hist  = (int*)(ws + off); off += 256;
  p.histv = (int*)(ws + off); off += 256;
  p.bar   = (unsigned*)(ws + off); off += 256;

  bar_init<<<1, 128, 0, stream>>>(p.bar);
  mega<<<NBLK, 256, 0, stream>>>(p);
}

// Round 7
// 29828.909 us; speedup vs baseline: 5.4407x; 5.4407x over previous
//
#include <hip/hip_runtime.h>
#include <hip/hip_bf16.h>
#include <stdint.h>

// ---------------------------------------------------------------------------
// BioDecoder: 64-step LSTM decoder w/ attention, rep-penalty, temperature=0.4,
// top-p=0.7, jax.random.categorical (Threefry partitionable). All fp32.
// Association discipline: every dot = strict sequential-k single-acc fma chain.
// R9: back to R6 launcher baseline (30.2ms; persistent-kernel path abandoned
// after R7/R8 regressions). Changes vs R6:
//  (1) register-resident sampler: 32 logits/thread in VGPRs, dlog+bo read
//      ONCE; Lbuf/Ebuf eliminated (E recomputed via bit-identical expf);
//      all trees/orders/integer sums identical to R6 -> bit-exact.
//  (2) gate GEMM fused into gate_attn (R8-proven-exact k-chain formula)
//      via once-transposed WgT built in init_state. 8 -> 7 launches/step.
// ---------------------------------------------------------------------------

#define B_   64
#define H_   1024
#define E_   512
#define DV_  512
#define KV_  49
#define V_   32000
#define T_   64

// ------------------------- Threefry-2x32-20 (JAX) --------------------------
__device__ __forceinline__ uint32_t rotl32(uint32_t x, int r) {
  return (x << r) | (x >> (32 - r));
}
__device__ __forceinline__ void tf2x32(uint32_t k0, uint32_t k1,
                                       uint32_t x0, uint32_t x1,
                                       uint32_t& o0, uint32_t& o1) {
  uint32_t ks0 = k0, ks1 = k1, ks2 = k0 ^ k1 ^ 0x1BD11BDAu;
  x0 += ks0; x1 += ks1;
#define RND_(r) { x0 += x1; x1 = rotl32(x1, r) ^ x0; }
  RND_(13) RND_(15) RND_(26) RND_(6)  x0 += ks1; x1 += ks2 + 1u;
  RND_(17) RND_(29) RND_(16) RND_(24) x0 += ks2; x1 += ks0 + 2u;
  RND_(13) RND_(15) RND_(26) RND_(6)  x0 += ks0; x1 += ks1 + 3u;
  RND_(17) RND_(29) RND_(16) RND_(24) x0 += ks1; x1 += ks2 + 4u;
  RND_(13) RND_(15) RND_(26) RND_(6)  x0 += ks2; x1 += ks0 + 5u;
#undef RND_
  o0 = x0; o1 = x1;
}

__device__ __forceinline__ unsigned key_of(float f) {
  unsigned u = __float_as_uint(f);
  return (u & 0x80000000u) ? ~u : (u | 0x80000000u);
}
__device__ __forceinline__ float sigf(float x) { return 1.0f / (1.0f + expf(-x)); }

// ------------------------- templated dual GEMM (verbatim R6) ---------------
template <int BN, int TM, int TN, int NTHR>
__global__ __launch_bounds__(NTHR)
void gemm_dq(const float* __restrict__ A0, int lda0, const float* __restrict__ W0,
             int ldw0, int K0, float* __restrict__ out0, int ldo0, int nt0,
             const float* __restrict__ A1, int lda1, const float* __restrict__ W1,
             int ldw1, int K1, float* __restrict__ out1, int ldo1) {
  constexpr int LD = 36;
  constexpr int ROWS = 64 + BN;
  constexpr int NF4 = ROWS * 8 / NTHR;
  constexpr int BUFST = ROWS * LD;
  constexpr int CG = BN / TN;
  static_assert(ROWS * 8 % NTHR == 0, "staging divisibility");
  static_assert((64 / TM) * CG == NTHR, "thread grid");
  static_assert(TN == 4, "float4 epilogue");
  __shared__ __align__(16) float S[2][ROWS][LD];

  const int tid = threadIdx.x;
  const int bx = blockIdx.x;
  const float* A; const float* W; float* out;
  int lda, ldw, K, ldo, n0;
  if (bx < nt0) { A = A0; W = W0; out = out0; lda = lda0; ldw = ldw0; K = K0; ldo = ldo0; n0 = bx * BN; }
  else          { A = A1; W = W1; out = out1; lda = lda1; ldw = ldw1; K = K1; ldo = ldo1; n0 = (bx - nt0) * BN; }
  const int m0 = blockIdx.y * 64;
  const int tc = tid % CG, tr = tid / CG;

  const float* gp[NF4];
  float* lp[NF4];
#pragma unroll
  for (int q = 0; q < NF4; ++q) {
    int l = tid + q * NTHR;
    int r = l >> 3, c4 = l & 7;
    gp[q] = (l < 512) ? (A + (m0 + r) * lda + c4 * 4)
                      : (W + (n0 + (r - 64)) * ldw + c4 * 4);
    lp[q] = &S[0][r][(c4 ^ ((r >> 2) & 7)) << 2];
  }

  float4 pre[NF4];
#pragma unroll
  for (int q = 0; q < NF4; ++q) pre[q] = *(const float4*)gp[q];
#pragma unroll
  for (int q = 0; q < NF4; ++q) *(float4*)lp[q] = pre[q];
  __syncthreads();

  float acc[TM][TN] = {};
  const int nch = K >> 5;
  for (int c = 0; c < nch; ++c) {
    const bool more = (c + 1 < nch);
    if (more) {
      const int kc = (c + 1) << 5;
#pragma unroll
      for (int q = 0; q < NF4; ++q) pre[q] = *(const float4*)(gp[q] + kc);
    }
    const float* Sb = &S[c & 1][0][0];
#pragma unroll
    for (int kk = 0; kk < 8; ++kk) {
      float4 a4[TM], w4[TN];
#pragma unroll
      for (int i = 0; i < TM; ++i) {
        int m = tr * TM + i;
        a4[i] = *(const float4*)(Sb + m * LD + ((kk ^ ((m >> 2) & 7)) << 2));
      }
#pragma unroll
      for (int j = 0; j < TN; ++j) {
        int rw = 64 + tc * TN + j;
        w4[j] = *(const float4*)(Sb + rw * LD + ((kk ^ ((rw >> 2) & 7)) << 2));
      }
#pragma unroll
      for (int i = 0; i < TM; ++i)
#pragma unroll
        for (int j = 0; j < TN; ++j) {
          acc[i][j] = fmaf(a4[i].x, w4[j].x, acc[i][j]);
          acc[i][j] = fmaf(a4[i].y, w4[j].y, acc[i][j]);
          acc[i][j] = fmaf(a4[i].z, w4[j].z, acc[i][j]);
          acc[i][j] = fmaf(a4[i].w, w4[j].w, acc[i][j]);
        }
    }
    if (more) {
      const int bo2 = ((c + 1) & 1) * BUFST;
#pragma unroll
      for (int q = 0; q < NF4; ++q) *(float4*)(lp[q] + bo2) = pre[q];
    }
    __syncthreads();
  }

#pragma unroll
  for (int i = 0; i < TM; ++i) {
    float4 o;
    o.x = acc[i][0]; o.y = acc[i][1]; o.z = acc[i][2]; o.w = acc[i][3];
    *(float4*)&out[(m0 + tr * TM + i) * ldo + n0 + tc * TN] = o;
  }
}

// ------------------------- LayerNorm for vp (verbatim R6) ------------------
__global__ __launch_bounds__(256)
void ln_vp(float* __restrict__ vp, const float* __restrict__ bv,
           const float* __restrict__ g, const float* __restrict__ bt) {
  int row = blockIdx.x, tid = threadIdx.x;
  __shared__ float buf[H_];
  __shared__ float red[256];
  float* p = vp + (long long)row * H_;
  for (int h = tid; h < H_; h += 256) buf[h] = __fadd_rn(p[h], bv[h]);
  __syncthreads();
  float s = 0;
  for (int h = tid; h < H_; h += 256) s += buf[h];
  red[tid] = s; __syncthreads();
  for (int off = 128; off > 0; off >>= 1) { if (tid < off) red[tid] += red[tid + off]; __syncthreads(); }
  float mu = red[0] / (float)H_;
  __syncthreads();
  float vs = 0;
  for (int h = tid; h < H_; h += 256) { float d = buf[h] - mu; vs += d * d; }
  red[tid] = vs; __syncthreads();
  for (int off = 128; off > 0; off >>= 1) { if (tid < off) red[tid] += red[tid + off]; __syncthreads(); }
  float var = red[0] / (float)H_;
  float sq = sqrtf(var + 1e-5f);
  for (int h = tid; h < H_; h += 256) {
    float nrm = __fdiv_rn(__fsub_rn(buf[h], mu), sq);
    p[h] = __fadd_rn(__fmul_rn(nrm, g[h]), bt[h]);
  }
}

// ------------------------- LSTM cell (verbatim R6) -------------------------
__global__ __launch_bounds__(256)
void lstm_cell2(const float* __restrict__ dx, const float* __restrict__ dh,
                const float* __restrict__ bih, const float* __restrict__ bhh,
                float* __restrict__ c,
                float* __restrict__ hA, int ldA, float* __restrict__ hB, int ldB) {
  int idx = blockIdx.x * 256 + threadIdx.x;      // 64*1024
  int b = idx >> 10, h = idx & 1023;
  float z[4];
#pragma unroll
  for (int g = 0; g < 4; g++) {
    int j = g * 1024 + h;
    float s = __fadd_rn(dx[b * 4096 + j], dh[b * 4096 + j]);
    s = __fadd_rn(s, bih[j]);
    s = __fadd_rn(s, bhh[j]);
    z[g] = s;
  }
  float fc = __fmul_rn(sigf(z[1]), c[idx]);
  float ig = __fmul_rn(sigf(z[0]), tanhf(z[2]));
  float cn = __fadd_rn(fc, ig);
  float hn = __fmul_rn(sigf(z[3]), tanhf(cn));
  c[idx] = cn;
  hA[(long long)b * ldA + h] = hn;
  hB[(long long)b * ldB + h] = hn;
}

// ------------------------- fused gate-GEMM + gate + attention --------------
// dg computed in-kernel: per output n, sequential k-chain (k ascending, one
// acc) over WgT[k][n] == Wg1[n][k] -> identical association to the old GEMM
// (fusion formula proven bit-exact in R8). Rest verbatim R6 gate_attn.
__global__ __launch_bounds__(256)
void gate_attn_f(const float* __restrict__ WgT, const float* __restrict__ bg1,
                 const float* __restrict__ Wg2, const float* __restrict__ bg2,
                 const float* __restrict__ h2buf, const float* __restrict__ vp,
                 float* __restrict__ ctx) {
  int b = blockIdx.x, tid = threadIdx.x;
  __shared__ float t1[H_], outv[H_], attn[64];
  __shared__ float gate_s;
  {
    float s0 = 0, s1 = 0, s2 = 0, s3 = 0;
    for (int k = 0; k < H_; ++k) {
      float hk = h2buf[b * H_ + k];          // wave-uniform -> scalar load
      const float* wr = WgT + k * H_;
      s0 = fmaf(hk, wr[tid], s0);
      s1 = fmaf(hk, wr[tid + 256], s1);
      s2 = fmaf(hk, wr[tid + 512], s2);
      s3 = fmaf(hk, wr[tid + 768], s3);
    }
    t1[tid]       = tanhf(__fadd_rn(s0, bg1[tid]));
    t1[tid + 256] = tanhf(__fadd_rn(s1, bg1[tid + 256]));
    t1[tid + 512] = tanhf(__fadd_rn(s2, bg1[tid + 512]));
    t1[tid + 768] = tanhf(__fadd_rn(s3, bg1[tid + 768]));
  }
  __syncthreads();
  if (tid == 0) {
    float s = 0;
    for (int h = 0; h < H_; h++) s = fmaf(t1[h], Wg2[h], s);
    gate_s = sigf(__fadd_rn(s, bg2[0]));
  }
  __syncthreads();
  float gate = gate_s;
  for (int h = tid; h < H_; h += 256) outv[h] = __fmul_rn(h2buf[b * H_ + h], gate);
  __syncthreads();
  if (tid < KV_) {
    const float* vrow = vp + ((long long)b * KV_ + tid) * H_;
    float a = 0;
    for (int h = 0; h < H_; h++) a = fmaf(outv[h], vrow[h], a);
    attn[tid] = __fmul_rn(a, 0.03125f);   // scale = 1/sqrt(1024)
  }
  __syncthreads();
  if (tid == 0) {
    float m = -INFINITY;
    for (int k = 0; k < KV_; k++) m = fmaxf(m, attn[k]);
    float ss = 0;
    for (int k = 0; k < KV_; k++) { attn[k] = expf(attn[k] - m); ss += attn[k]; }
    for (int k = 0; k < KV_; k++) attn[k] = __fdiv_rn(attn[k], ss);
  }
  __syncthreads();
  for (int h = tid; h < H_; h += 256) {
    float acc = 0;
    for (int k = 0; k < KV_; k++) acc = fmaf(attn[k], vp[((long long)b * KV_ + k) * H_ + h], acc);
    ctx[b * H_ + h] = __fadd_rn(outv[h], acc);
  }
}

// ------------------------- init (+ WgT transpose) --------------------------
__global__ __launch_bounds__(256)
void init_state(const float* __restrict__ thought, const float* __restrict__ embedding,
                const float* __restrict__ Wg1, float* __restrict__ WgT,
                float* c1, float* c2, float* xcat1, float* xcat2,
                int* hist, int* histv) {
  int i = blockIdx.x * 256 + threadIdx.x;
  if (i < B_ * H_) {
    int b = i >> 10, h = i & 1023;
    c1[i] = 0.f; c2[i] = 0.f;
    float th = thought[i];
    xcat1[b * (E_ + H_) + E_ + h] = th;   // h1_0 = thought
    xcat2[b * (2 * H_) + H_ + h] = th;    // h2_0 = thought
    if (h < E_) xcat1[b * (E_ + H_) + h] = embedding[E_ + h];  // token 1
  }
  if (i < B_ * 3) { hist[i] = 0; histv[i] = 0; }
  // WgT[k][j] = Wg1[j][k]; write-coalesced gather
  for (int x = i; x < H_ * H_; x += 256 * 256) {
    int k = x >> 10, j = x & 1023;
    WgT[x] = Wg1[j * H_ + k];
  }
}

// ------------------------- sampling (register-resident) --------------------
// 32 logits/thread in VGPRs (fully unrolled, static indexing). dlog+bo read
// once; no Lbuf/Ebuf. E recomputed via expf (same input bits -> same output
// bits as R6's stored float). All trees/orders/integer sums verbatim R6 ->
// bit-identical selection.
__global__ __launch_bounds__(1024)
void sample_kernel(const float* __restrict__ dlog, const float* __restrict__ bo,
                   int* __restrict__ hist, int* __restrict__ histv,
                   const float* __restrict__ embedding, float* __restrict__ xcat1,
                   int* __restrict__ outTok, int t) {
  int b = blockIdx.x, tid = threadIdx.x;
  __shared__ float redf[1024];
  __shared__ int   redi[1024];
  __shared__ unsigned long long whist[8][257];   // 16.4 KB, bank-staggered
  __shared__ unsigned long long suf[256];
  __shared__ unsigned long long wq[4];
  __shared__ int jstar_s;
  __shared__ unsigned long long carry_s;
  __shared__ unsigned prefix_s;

  int hh0 = hist[b * 3 + 0], hh1 = hist[b * 3 + 1], hh2 = hist[b * 3 + 2];
  int p0 = histv[b * 3 + 0] ? hh0 : -1;
  int p1 = histv[b * 3 + 1] ? hh1 : -1;
  int p2 = histv[b * 3 + 2] ? hh2 : -1;
  const float* pa = dlog + (long long)b * V_;

  // pass 1: scaled logits into registers + max (same per-thread order as R6)
  float L[32];
  float lm = -INFINITY;
#pragma unroll
  for (int e = 0; e < 32; ++e) {
    int v = tid + (e << 10);
    float l = -INFINITY;
    if (v < V_) {
      float raw = __fadd_rn(pa[v], bo[v]);
      if (v == p0 || v == p1 || v == p2) raw = __fsub_rn(raw, 2.0f);
      l = __fdiv_rn(raw, 0.4f);
      lm = fmaxf(lm, l);
    }
    L[e] = l;
  }
  redf[tid] = lm; __syncthreads();
  for (int off = 512; off > 0; off >>= 1) { if (tid < off) redf[tid] = fmaxf(redf[tid], redf[tid + off]); __syncthreads(); }
  float m = redf[0];
  __syncthreads();

  // pass 2: exp + sum (per-thread ascending order, same tree)
  float ls = 0;
#pragma unroll
  for (int e = 0; e < 32; ++e) {
    int v = tid + (e << 10);
    if (v < V_) ls += expf(L[e] - m);
  }
  redf[tid] = ls; __syncthreads();
  for (int off = 512; off > 0; off >>= 1) { if (tid < off) redf[tid] += redf[tid + off]; __syncthreads(); }
  float Z = redf[0];
  __syncthreads();

  // radix select: K* = key of smallest kept token; kept iff mass(keys>k) <= 0.7f
  const double SC = 17592186044416.0; // 2^44
  const unsigned long long B0 =
      (unsigned long long)(0.699999988079071044921875 * 17592186044416.0); // (double)0.7f * 2^44
  if (tid == 0) { carry_s = 0ull; prefix_s = 0u; }
  __syncthreads();
  const int wid = tid >> 7;   // 8 sub-histograms (2 waves each)
  for (int pass = 0; pass < 4; pass++) {
    int shift = 24 - 8 * pass;
    unsigned maskk = (pass == 0) ? 0u : (0xFFFFFFFFu << (shift + 8));
    for (int i = tid; i < 8 * 257; i += 1024) ((unsigned long long*)whist)[i] = 0ull;
    __syncthreads();
    unsigned pref = prefix_s;
    unsigned long long carry = carry_s;
#pragma unroll
    for (int e = 0; e < 32; ++e) {
      int v = tid + (e << 10);
      if (v < V_) {
        unsigned key = key_of(L[e]);
        if ((key & maskk) == pref) {
          unsigned bin = (key >> shift) & 255u;
          float ee = expf(L[e] - m);   // bit-identical to R6's stored E
          unsigned long long S = (unsigned long long)((double)(ee / Z) * SC);
          atomicAdd(&whist[wid][bin], (S << 16) | 1ull);
        }
      }
    }
    __syncthreads();

    // reduce 8 histograms + shfl suffix scan over 256 bins (tid<256)
    unsigned long long bs = 0ull;
    if (tid < 256) {
#pragma unroll
      for (int w = 0; w < 8; ++w) bs += whist[w][tid];
    }
    if (tid == 0) jstar_s = 256;
    __syncthreads();
    unsigned long long sown = 0ull, sincl = 0ull;
    if (tid < 256) {
      sown = bs >> 16;
      sincl = sown;
#pragma unroll
      for (int off = 1; off < 64; off <<= 1) {
        unsigned long long o = __shfl_down(sincl, off);
        if ((tid & 63) + off < 64) sincl += o;
      }
      if ((tid & 63) == 0) wq[tid >> 6] = sincl;
    }
    __syncthreads();
    if (tid < 256) {
      unsigned long long add = 0ull;
      for (int w2 = (tid >> 6) + 1; w2 < 4; ++w2) add += wq[w2];
      suf[tid] = sincl + add - sown;       // mass strictly above bin tid
    }
    __syncthreads();
    if (tid < 256 && (unsigned)(bs & 0xFFFFull) > 0u) {
      unsigned long long A = carry + suf[tid];
      if (A <= B0) atomicMin(&jstar_s, tid);
    }
    __syncthreads();
    if (tid == 0) {
      int j = jstar_s;
      carry_s = carry + suf[j];
      prefix_s = pref | (((unsigned)j) << shift);
    }
    __syncthreads();
  }
  unsigned Kstar = prefix_s;

  // step key (partitionable foldlike split of key(42))
  unsigned kt0, kt1;
  tf2x32(0u, 42u, 0u, (unsigned)t, kt0, kt1);

  // gumbel argmax over kept set (registers; same order + tree as R6)
  float bestv = -INFINITY; int besti = 0x7fffffff;
#pragma unroll
  for (int e = 0; e < 32; ++e) {
    int v = tid + (e << 10);
    if (v < V_) {
      float l = L[e];
      if (key_of(l) >= Kstar) {
        unsigned r0, r1;
        tf2x32(kt0, kt1, 0u, (unsigned)(b * V_ + v), r0, r1);
        unsigned bits = r0 ^ r1;
        float u = __uint_as_float((bits >> 9) | 0x3f800000u) - 1.0f;
        u = fmaxf(u, 1.17549435e-38f);
        float gum = -logf(-logf(u));
        float val = __fadd_rn(l, gum);
        if (val > bestv) { bestv = val; besti = v; }
      }
    }
  }
  redf[tid] = bestv; redi[tid] = besti; __syncthreads();
  for (int off = 512; off > 0; off >>= 1) {
    if (tid < off) {
      float ov = redf[tid + off]; int oi = redi[tid + off];
      if (ov > redf[tid] || (ov == redf[tid] && oi < redi[tid])) { redf[tid] = ov; redi[tid] = oi; }
    }
    __syncthreads();
  }
  int tok = redi[0];
  if (tid == 0) {
    outTok[b * T_ + t] = tok;
    hist[b * 3 + 0] = hh1; hist[b * 3 + 1] = hh2; hist[b * 3 + 2] = tok;
    int v1 = histv[b * 3 + 1], v2 = histv[b * 3 + 2];
    histv[b * 3 + 0] = v1; histv[b * 3 + 1] = v2; histv[b * 3 + 2] = 1;
  }
  // next-step embedding gather
  for (int k = tid; k < E_; k += 1024)
    xcat1[b * (E_ + H_) + k] = embedding[(long long)tok * E_ + k];
}

// ---------------------------------------------------------------------------
extern "C" void kernel_launch(void* const* d_in, const int* in_sizes, int n_in,
                              void* d_out, int out_size, void* d_ws, size_t ws_size,
                              hipStream_t stream) {
  const float* thought   = (const float*)d_in[0];
  const float* visf      = (const float*)d_in[1];
  const float* embedding = (const float*)d_in[3];
  const float* Wih1 = (const float*)d_in[4];
  const float* Whh1 = (const float*)d_in[5];
  const float* bih1 = (const float*)d_in[6];
  const float* bhh1 = (const float*)d_in[7];
  const float* Wih2 = (const float*)d_in[8];
  const float* Whh2 = (const float*)d_in[9];
  const float* bih2 = (const float*)d_in[10];
  const float* bhh2 = (const float*)d_in[11];
  const float* Wg1  = (const float*)d_in[12];
  const float* bg1  = (const float*)d_in[13];
  const float* Wg2  = (const float*)d_in[14];
  const float* bg2  = (const float*)d_in[15];
  const float* Wo   = (const float*)d_in[16];
  const float* bo   = (const float*)d_in[17];
  const float* Wv   = (const float*)d_in[18];
  const float* bv   = (const float*)d_in[19];
  const float* ln_g = (const float*)d_in[20];
  const float* ln_b = (const float*)d_in[21];
  int* outTok = (int*)d_out;

  // workspace layout (floats)
  float* ws = (float*)d_ws;
  long long off = 0;
  float* vp    = ws + off; off += (long long)B_ * KV_ * H_;   // 3,211,264
  float* xcat1 = ws + off; off += B_ * (E_ + H_);
  float* xcat2 = ws + off; off += B_ * (2 * H_);
  float* c1    = ws + off; off += B_ * H_;
  float* c2    = ws + off; off += B_ * H_;
  float* h2buf = ws + off; off += B_ * H_;
  float* ctx   = ws + off; off += B_ * H_;
  float* dx    = ws + off; off += (long long)B_ * 4096;
  float* dh    = ws + off; off += (long long)B_ * 4096;
  float* dlog  = ws + off; off += (long long)B_ * V_;
  float* WgT   = ws + off; off += (long long)H_ * H_;
  int* hist  = (int*)(ws + off); off += 256;   // 192 used, padded
  int* histv = (int*)(ws + off); off += 256;   // 192 used, padded

  // init recurrent state + WgT transpose
  init_state<<<256, 256, 0, stream>>>(thought, embedding, Wg1, WgT,
                                      c1, c2, xcat1, xcat2, hist, histv);

  // visual_proj: vp_pre = visf @ Wv^T (M=3136, N=1024, K=512), then LN(+bv)
  gemm_dq<128, 8, 4, 256><<<dim3(8, KV_), 256, 0, stream>>>(
      visf, DV_, Wv, DV_, DV_, vp, H_, 8,
      visf, DV_, Wv, DV_, DV_, vp, H_);
  ln_vp<<<B_ * KV_, 256, 0, stream>>>(vp, bv, ln_g, ln_b);

  for (int t = 0; t < T_; t++) {
    // layer 1: dx = emb @ Wih1^T (K=512), dh = h1 @ Whh1^T (K=1024) — one launch
    gemm_dq<32, 4, 4, 128><<<dim3(256, 1), 128, 0, stream>>>(
        xcat1, E_ + H_, Wih1, E_, E_, dx, 4096, 128,
        xcat1 + E_, E_ + H_, Whh1, H_, H_, dh, 4096);
    lstm_cell2<<<256, 256, 0, stream>>>(dx, dh, bih1, bhh1, c1,
                                        xcat1 + E_, E_ + H_, xcat2, 2 * H_);
    // layer 2: dx = h1 @ Wih2^T, dh = h2 @ Whh2^T — one launch
    gemm_dq<32, 4, 4, 128><<<dim3(256, 1), 128, 0, stream>>>(
        xcat2, 2 * H_, Wih2, H_, H_, dx, 4096, 128,
        xcat2 + H_, 2 * H_, Whh2, H_, H_, dh, 4096);
    lstm_cell2<<<256, 256, 0, stream>>>(dx, dh, bih2, bhh2, c2,
                                        h2buf, H_, xcat2 + H_, 2 * H_);
    // fused gate-GEMM + gate + attention (64 blocks)
    gate_attn_f<<<B_, 256, 0, stream>>>(WgT, bg1, Wg2, bg2, h2buf, vp, ctx);
    // logits = ctx @ Wo^T (N=32000 -> 250 blocks of BN=128)
    gemm_dq<128, 8, 4, 256><<<dim3(250, 1), 256, 0, stream>>>(
        ctx, H_, Wo, H_, H_, dlog, V_, 250,
        ctx, H_, Wo, H_, H_, dlog, V_);
    sample_kernel<<<B_, 1024, 0, stream>>>(dlog, bo, hist, histv,
                                           embedding, xcat1, outTok, t);
  }
}